// Round 1
// baseline (186.256 us; speedup 1.0000x reference)
//
#include <hip/hip_runtime.h>

#define SQL  1024
#define EDIM 256
#define NHD  8
#define NKV  (NHD * 3 * EDIM)   // 6144
#define MROWS (4 * SQL)         // 4096

typedef short bf16x8 __attribute__((ext_vector_type(8)));
typedef float f32x4 __attribute__((ext_vector_type(4)));

__device__ __forceinline__ unsigned short f2bf(float f) {
  unsigned u = __float_as_uint(f);
  u += 0x7fff + ((u >> 16) & 1);   // round-to-nearest-even (finite values)
  return (unsigned short)(u >> 16);
}

// async 16B global->LDS (direct-to-shared DMA; LDS dest must be
// wave-uniform base + lane*16 — all call sites use flat (it*256+tid)*16B)
__device__ __forceinline__ void g2lds16(const void* g, void* l) {
  __builtin_amdgcn_global_load_lds(
      (const __attribute__((address_space(1))) unsigned int*)g,
      (__attribute__((address_space(3))) unsigned int*)l, 16, 0, 0);
}

// packed 4-element C store (lane holds 4 consecutive-n values)
__device__ __forceinline__ void store4(unsigned short* p, float4 v) {
  union { unsigned short s[4]; uint2 u; } t;
  t.s[0] = f2bf(v.x); t.s[1] = f2bf(v.y); t.s[2] = f2bf(v.z); t.s[3] = f2bf(v.w);
  *(uint2*)p = t.u;
}
__device__ __forceinline__ void store4(float* p, float4 v) { *(float4*)p = v; }

// =====================================================================
// fused fp32 -> bf16 cast for all three inputs, 8 elems/thread.
// Segment sizes are multiples of 256*8 so blocks never straddle.
// =====================================================================
__global__ __launch_bounds__(256) void cast3_bf16(
    const float* __restrict__ s0, unsigned short* __restrict__ d0, int n0,
    const float* __restrict__ s1, unsigned short* __restrict__ d1, int n1,
    const float* __restrict__ s2, unsigned short* __restrict__ d2, int n2) {
  int i = blockIdx.x * 256 + threadIdx.x;
  const float* s; unsigned short* d;
  if (i < n0) { s = s0; d = d0; }
  else if (i < n0 + n1) { i -= n0; s = s1; d = d1; }
  else { i -= n0 + n1; if (i >= n2) return; s = s2; d = d2; }
  float4 a = ((const float4*)s)[2 * i];
  float4 b = ((const float4*)s)[2 * i + 1];
  union { unsigned short u[8]; ulonglong2 v; } t;
  t.u[0] = f2bf(a.x); t.u[1] = f2bf(a.y); t.u[2] = f2bf(a.z); t.u[3] = f2bf(a.w);
  t.u[4] = f2bf(b.x); t.u[5] = f2bf(b.y); t.u[6] = f2bf(b.z); t.u[7] = f2bf(b.w);
  ((ulonglong2*)d)[i] = t.v;
}

// =====================================================================
// bf16 MFMA NT-GEMM, double-buffered global_load_lds staging.
// mfma args are SWAPPED (bf, af): each lane then holds 4 consecutive-n
// output values (D-layout row index = reg), so the C store is one packed
// 8B/16B store per (i,j) tile instead of 4 scalar stores — 4x fewer
// store instructions for the 50MB proj write, float4 bias loads.
// =====================================================================
template <int BM, int BN, typename OutT>
__global__ __launch_bounds__(256) void gemm_mfma(
    const unsigned short* __restrict__ A, const unsigned short* __restrict__ B,
    const float* __restrict__ bias, OutT* __restrict__ C,
    int M, int N, int K) {
  constexpr int TM = BM / 32, TN = BN / 32;
  __shared__ __align__(16) unsigned short As[2][BM * 32];
  __shared__ __align__(16) unsigned short Bs[2][BN * 32];
  const int tid = threadIdx.x;
  const int wave = tid >> 6, lane = tid & 63;
  const int quad = lane >> 4, l16 = lane & 15;
  const int wm = (wave >> 1) * (BM / 2), wn = (wave & 1) * (BN / 2);
  const int m0 = blockIdx.x * BM, n0 = blockIdx.y * BN;
  const int sw = (l16 >> 1) & 3;

  f32x4 acc[TM][TN];
  #pragma unroll
  for (int i = 0; i < TM; i++)
    #pragma unroll
    for (int j = 0; j < TN; j++) acc[i][j] = {0.f, 0.f, 0.f, 0.f};

  auto stage = [&](int k0, int bb) {
    #pragma unroll
    for (int it = 0; it < BM / 64; it++) {
      int flat = it * 256 + tid;
      int row = flat >> 2;
      int cg = (flat & 3) ^ ((row >> 1) & 3);
      g2lds16(A + (size_t)(m0 + row) * K + k0 + cg * 8, &As[bb][flat * 8]);
    }
    #pragma unroll
    for (int it = 0; it < BN / 64; it++) {
      int flat = it * 256 + tid;
      int row = flat >> 2;
      int cg = (flat & 3) ^ ((row >> 1) & 3);
      g2lds16(B + (size_t)(n0 + row) * K + k0 + cg * 8, &Bs[bb][flat * 8]);
    }
  };

  stage(0, 0);
  __syncthreads();
  for (int k0 = 0; k0 < K; k0 += 32) {
    const int bb = (k0 >> 5) & 1;
    if (k0 + 32 < K) stage(k0 + 32, bb ^ 1);
    bf16x8 af[TM], bf[TN];
    #pragma unroll
    for (int i = 0; i < TM; i++)
      af[i] = *(const bf16x8*)&As[bb][(wm + i * 16 + l16) * 32 + (quad ^ sw) * 8];
    #pragma unroll
    for (int j = 0; j < TN; j++)
      bf[j] = *(const bf16x8*)&Bs[bb][(wn + j * 16 + l16) * 32 + (quad ^ sw) * 8];
    #pragma unroll
    for (int i = 0; i < TM; i++)
      #pragma unroll
      for (int j = 0; j < TN; j++)
        acc[i][j] = __builtin_amdgcn_mfma_f32_16x16x32_bf16(bf[j], af[i], acc[i][j], 0, 0, 0);
    __syncthreads();  // gates buffer reuse + drains this iter's prefetch
  }

  // epilogue: lane holds C[m = wm+i*16+l16][n = nb..nb+3] (transposed tile)
  #pragma unroll
  for (int j = 0; j < TN; j++) {
    const int nb = n0 + wn + j * 16 + quad * 4;
    const float4 bias4 = *(const float4*)&bias[nb];
    #pragma unroll
    for (int i = 0; i < TM; i++) {
      const int m = m0 + wm + i * 16 + l16;
      float4 v = {acc[i][j][0] + bias4.x, acc[i][j][1] + bias4.y,
                  acc[i][j][2] + bias4.z, acc[i][j][3] + bias4.w};
      store4(&C[(size_t)m * N + nb], v);
    }
  }
}

// =====================================================================
// One-shot V transpose: raw-view V -> Vt[bh][d][s] bf16.
// =====================================================================
__global__ __launch_bounds__(256) void transpose_v(
    const unsigned short* __restrict__ proj, unsigned short* __restrict__ vt) {
  __shared__ unsigned short T[64][66];
  const int tid = threadIdx.x;
  const int s0 = blockIdx.x * 64, d0 = blockIdx.y * 64, bh = blockIdx.z;
  const int b = bh >> 3, h = bh & 7;
  #pragma unroll
  for (int it = 0; it < 2; it++) {
    int c = it * 256 + tid;
    int sr = c >> 3, k8 = (c & 7) * 8;
    int s = s0 + sr;
    const unsigned short* src = proj + (size_t)(b * SQL + h * 128 + (s >> 3)) * NKV
                                + 2 * 2048 + (s & 7) * 256 + d0 + k8;
    *(ulonglong2*)&T[sr][k8] = *(const ulonglong2*)src;
  }
  __syncthreads();
  #pragma unroll
  for (int it = 0; it < 2; it++) {
    int c = it * 256 + tid;
    int dr = c >> 3, s8 = (c & 7) * 8;
    unsigned short tmp[8];
    #pragma unroll
    for (int j = 0; j < 8; j++) tmp[j] = T[s8 + j][dr];
    unsigned short* dst = vt + ((size_t)bh * EDIM + d0 + dr) * SQL + s0 + s8;
    *(ulonglong2*)dst = *(ulonglong2*)tmp;
  }
}

// =====================================================================
// bf16 MFMA flash attention, round 5: wave role-split to halve LDS reads.
//  - wave (qh,kh): QK^T computes S rows qh*32..+31 x k-cols kh*16..+15;
//    each K B-frag read feeds 2 MFMAs (q-subtiles). K redundancy 4x->2x.
//  - wave (qh,dh=kh): PV computes O rows qh*32..+31 x d-cols dh*128..+127;
//    each V B-frag read feeds 2 MFMAs. V redundancy 4x->2x.
//  - P crosses waves (k-halves) -> one lgkm-only raw s_barrier mid-iter
//    (no vmcnt drain: prefetch stays in flight to the end barrier).
//  - l partials per (qh,kh) combined via tiny LDS array in epilogue.
//  - qh=0 waves skip the fully-masked final diagonal tile.
// Per-wave/iter ds_read_b128: 18 (8 K + 2 P + 8 V) vs 33 before.
// LDS: Ks0|Vts0|Ks1|Vts1 (8KB each, 32KB dbuf total... 64KB) + Ps 5KB
// + lsum 0.5KB = 71.2KB -> 2 blocks/CU (unchanged).
// =====================================================================
__global__ __launch_bounds__(256, 2) void attn_mfma(
    const unsigned short* __restrict__ proj,
    const unsigned short* __restrict__ vt,
    unsigned short* __restrict__ oflat) {
  // shorts: Ks0 @0 (8192) | Vts0 @8192 | Ks1 @16384 | Vts1 @24576 | Ps @32768 (2560)
  __shared__ __align__(16) unsigned short lds[35328];
  __shared__ float lsum[2][64];
  unsigned short* Ps = lds + 32768;  // [64][40] padded

  const int tid = threadIdx.x;
  const int wave = tid >> 6, lane = tid & 63;
  const int quad = lane >> 4, l16 = lane & 15;
  const int qh = wave >> 1;   // q-row half: rows qh*32..qh*32+31
  const int kh = wave & 1;    // QK^T k-16-col half; PV d-128 half
  // balanced decode: slot s -> (bh = s&31, j = s>>5); round 0 heavy, 1 light
  const int slot = blockIdx.x & 255, round = blockIdx.x >> 8;
  const int bh = slot & 31;
  const int jj = slot >> 5;
  const int qt = round ? jj : 15 - jj;
  const int b = bh >> 3, h = bh & 7;
  const int q0 = qt * 64;

  // ---- stage Q (64 x 256) through buf0 region, swizzled ----
  #pragma unroll
  for (int it = 0; it < 8; it++) {
    int c = it * 256 + tid;
    int r = c >> 5, ch = (c & 31) ^ (r & 7);
    int s = q0 + r;
    g2lds16(proj + (size_t)(b * SQL + h * 128 + (s >> 3)) * NKV + (s & 7) * 256 + ch * 8,
            lds + c * 8);
  }
  __syncthreads();
  bf16x8 aq[2][8];
  #pragma unroll
  for (int qs = 0; qs < 2; qs++) {
    const int qrow = qh * 32 + qs * 16 + l16;
    #pragma unroll
    for (int kk = 0; kk < 8; kk++)
      aq[qs][kk] = *(const bf16x8*)&lds[qrow * 256 + ((kk * 4 + quad) ^ (qrow & 7)) * 8];
  }
  __syncthreads();  // all waves done reading Q before buf0 overwrite

  f32x4 o[2][8];
  #pragma unroll
  for (int qs = 0; qs < 2; qs++)
    #pragma unroll
    for (int tl = 0; tl < 8; tl++) o[qs][tl] = {0.f, 0.f, 0.f, 0.f};
  float l_r[2][4] = {{0.f, 0.f, 0.f, 0.f}, {0.f, 0.f, 0.f, 0.f}};

  auto stage = [&](int kt, int bb) {
    unsigned short* KsB = lds + bb * 16384;
    unsigned short* VtB = KsB + 8192;
    #pragma unroll
    for (int it = 0; it < 4; it++) {   // K tile 32 x 256
      int c = it * 256 + tid;
      int r = c >> 5, ch = (c & 31) ^ (r & 7);
      int s = kt * 32 + r;
      g2lds16(proj + (size_t)(b * SQL + h * 128 + (s >> 3)) * NKV + 2048 + (s & 7) * 256 + ch * 8,
              KsB + c * 8);
    }
    #pragma unroll
    for (int it = 0; it < 4; it++) {   // Vt tile 256 x 32
      int c = it * 256 + tid;
      int d = c >> 2, ch = (c & 3) ^ (d & 3);
      g2lds16(vt + ((size_t)bh * EDIM + d) * SQL + kt * 32 + ch * 8, VtB + c * 8);
    }
  };

  const int nkt = 2 * qt + 2;
  stage(0, 0);
  __syncthreads();  // drain kt=0 (exposed once)

  for (int kt = 0; kt < nkt; kt++) {
    const int bb = kt & 1;
    if (kt + 1 < nkt) stage(kt + 1, bb ^ 1);  // prefetch into other buffer
    const unsigned short* KsB = lds + bb * 16384;
    const unsigned short* VtB = KsB + 8192;
    // qh=0 waves are fully masked on the last (diagonal) tile
    const bool live = (kt * 32 <= q0 + qh * 32 + 31);

    if (live) {
      // ---- S = Q K^T : rows qh*32..+31, cols kh*16..+15; bk shared by both qs ----
      f32x4 s0 = {0.f, 0.f, 0.f, 0.f}, s1 = {0.f, 0.f, 0.f, 0.f};
      const int krow = kh * 16 + l16;
      #pragma unroll
      for (int kk = 0; kk < 8; kk++) {
        bf16x8 bk = *(const bf16x8*)&KsB[krow * 256 + ((kk * 4 + quad) ^ (krow & 7)) * 8];
        s0 = __builtin_amdgcn_mfma_f32_16x16x32_bf16(aq[0][kk], bk, s0, 0, 0, 0);
        s1 = __builtin_amdgcn_mfma_f32_16x16x32_bf16(aq[1][kk], bk, s1, 0, 0, 0);
      }
      // ---- shift-free softmax: p = exp2(s * 0.0625*log2e), lane-local l ----
      const int kg = kt * 32 + kh * 16 + l16;
      #pragma unroll
      for (int r = 0; r < 4; r++) {
        const int qg0 = q0 + qh * 32 + quad * 4 + r;
        float p0 = (kg <= qg0)      ? exp2f(s0[r] * 0.09016844f) : 0.f;
        float p1 = (kg <= qg0 + 16) ? exp2f(s1[r] * 0.09016844f) : 0.f;
        l_r[0][r] += p0;
        l_r[1][r] += p1;
        Ps[(qh * 32 + quad * 4 + r) * 40 + kh * 16 + l16]        = f2bf(p0);
        Ps[(qh * 32 + 16 + quad * 4 + r) * 40 + kh * 16 + l16]   = f2bf(p1);
      }
    }
    // mid barrier: lgkm-only (P visibility) — leaves prefetch vmcnt in flight
    asm volatile("s_waitcnt lgkmcnt(0)\n\ts_barrier" ::: "memory");
    if (live) {
      // ---- PV: rows qh*32..+31, d-cols kh*128..+127; bv shared by both qs ----
      bf16x8 ap0 = *(const bf16x8*)&Ps[(qh * 32 + l16) * 40 + quad * 8];
      bf16x8 ap1 = *(const bf16x8*)&Ps[(qh * 32 + 16 + l16) * 40 + quad * 8];
      #pragma unroll
      for (int tl = 0; tl < 8; tl++) {
        const int vrow = kh * 128 + tl * 16 + l16;
        bf16x8 bv = *(const bf16x8*)&VtB[vrow * 32 + (quad ^ (l16 & 3)) * 8];
        o[0][tl] = __builtin_amdgcn_mfma_f32_16x16x32_bf16(ap0, bv, o[0][tl], 0, 0, 0);
        o[1][tl] = __builtin_amdgcn_mfma_f32_16x16x32_bf16(ap1, bv, o[1][tl], 0, 0, 0);
      }
    }
    __syncthreads();  // buffer+Ps reuse gate + drains this iter's prefetch
  }

  // ---- epilogue: reduce l across 16-lane group, combine k-halves via LDS ----
  #pragma unroll
  for (int qs = 0; qs < 2; qs++)
    #pragma unroll
    for (int r = 0; r < 4; r++) {
      float l = l_r[qs][r];
      #pragma unroll
      for (int off = 1; off < 16; off <<= 1) l += __shfl_xor(l, off);
      if (l16 == 0) lsum[kh][qh * 32 + qs * 16 + quad * 4 + r] = l;
    }
  __syncthreads();
  #pragma unroll
  for (int qs = 0; qs < 2; qs++) {
    #pragma unroll
    for (int r = 0; r < 4; r++) {
      const int row = qh * 32 + qs * 16 + quad * 4 + r;
      const float inv = 1.0f / (lsum[0][row] + lsum[1][row]);
      const int s = q0 + row;
      unsigned short* dst = oflat + (size_t)(b * SQL + h * 128 + (s >> 3)) * 2048
                            + (s & 7) * 256 + kh * 128;
      #pragma unroll
      for (int tl = 0; tl < 8; tl++)
        dst[tl * 16 + l16] = f2bf(o[qs][tl][r] * inv);
    }
  }
}

extern "C" void kernel_launch(void* const* d_in, const int* in_sizes, int n_in,
                              void* d_out, int out_size, void* d_ws, size_t ws_size,
                              hipStream_t stream) {
  const float* x      = (const float*)d_in[0];
  const float* w_attn = (const float*)d_in[1];
  const float* b_attn = (const float*)d_in[2];
  const float* w_out  = (const float*)d_in[3];
  const float* b_out  = (const float*)d_in[4];
  float* out = (float*)d_out;

  char* p = (char*)d_ws;
  unsigned short* proj = (unsigned short*)p;  p += (size_t)MROWS * NKV * 2;
  unsigned short* obf  = (unsigned short*)p;  p += (size_t)MROWS * 2048 * 2;
  unsigned short* vtb  = (unsigned short*)p;  p += (size_t)32 * EDIM * SQL * 2;
  unsigned short* xb   = (unsigned short*)p;  p += (size_t)MROWS * EDIM * 2;
  unsigned short* wb   = (unsigned short*)p;  p += (size_t)NKV * EDIM * 2;
  unsigned short* wob  = (unsigned short*)p;

  const int n0 = MROWS * EDIM / 8;        // 131072 -> 512 blocks
  const int n1 = NKV * EDIM / 8;          // 196608 -> 768 blocks
  const int n2 = EDIM * 2048 / 8;         // 65536  -> 256 blocks
  cast3_bf16<<<(n0 + n1 + n2) / 256, 256, 0, stream>>>(x, xb, n0, w_attn, wb, n1,
                                                       w_out, wob, n2);

  gemm_mfma<128, 128, unsigned short><<<dim3(MROWS / 128, NKV / 128), 256, 0, stream>>>(
      xb, wb, b_attn, proj, MROWS, NKV, EDIM);
  transpose_v<<<dim3(SQL / 64, EDIM / 64, 32), 256, 0, stream>>>(proj, vtb);
  attn_mfma<<<512, 256, 0, stream>>>(proj, vtb, obf);
  gemm_mfma<64, 64, float><<<dim3(MROWS / 64, EDIM / 64), 256, 0, stream>>>(
      obf, wob, b_out, out, MROWS, EDIM, NHD * EDIM);
}

// Round 3
// 171.962 us; speedup vs baseline: 1.0831x; 1.0831x over previous
//
#include <hip/hip_runtime.h>

#define SQL  1024
#define EDIM 256
#define NHD  8
#define NKV  (NHD * 3 * EDIM)   // 6144
#define MROWS (4 * SQL)         // 4096

typedef short bf16x8 __attribute__((ext_vector_type(8)));
typedef float f32x4 __attribute__((ext_vector_type(4)));

__device__ __forceinline__ unsigned short f2bf(float f) {
  unsigned u = __float_as_uint(f);
  u += 0x7fff + ((u >> 16) & 1);   // round-to-nearest-even (finite values)
  return (unsigned short)(u >> 16);
}

// async 16B global->LDS (direct-to-shared DMA; LDS dest must be
// wave-uniform base + lane*16 — all call sites use flat (it*T+tid)*16B)
__device__ __forceinline__ void g2lds16(const void* g, void* l) {
  __builtin_amdgcn_global_load_lds(
      (const __attribute__((address_space(1))) unsigned int*)g,
      (__attribute__((address_space(3))) unsigned int*)l, 16, 0, 0);
}

__device__ __forceinline__ void storev(float* p, float v) { *p = v; }
__device__ __forceinline__ void storev(unsigned short* p, float v) { *p = f2bf(v); }

// =====================================================================
// fused fp32 -> bf16 cast for all three inputs, 8 elems/thread.
// Segment sizes are multiples of 256*8 so blocks never straddle.
// =====================================================================
__global__ __launch_bounds__(256) void cast3_bf16(
    const float* __restrict__ s0, unsigned short* __restrict__ d0, int n0,
    const float* __restrict__ s1, unsigned short* __restrict__ d1, int n1,
    const float* __restrict__ s2, unsigned short* __restrict__ d2, int n2) {
  int i = blockIdx.x * 256 + threadIdx.x;
  const float* s; unsigned short* d;
  if (i < n0) { s = s0; d = d0; }
  else if (i < n0 + n1) { i -= n0; s = s1; d = d1; }
  else { i -= n0 + n1; if (i >= n2) return; s = s2; d = d2; }
  float4 a = ((const float4*)s)[2 * i];
  float4 b = ((const float4*)s)[2 * i + 1];
  union { unsigned short u[8]; ulonglong2 v; } t;
  t.u[0] = f2bf(a.x); t.u[1] = f2bf(a.y); t.u[2] = f2bf(a.z); t.u[3] = f2bf(a.w);
  t.u[4] = f2bf(b.x); t.u[5] = f2bf(b.y); t.u[6] = f2bf(b.z); t.u[7] = f2bf(b.w);
  ((ulonglong2*)d)[i] = t.v;
}

// =====================================================================
// bf16 MFMA NT-GEMM, double-buffered global_load_lds staging.
// (round-0 proven version: mfma(af,bf), scalar C stores — the packed
// transposed-store variant of round 1 was uncoalesced and regressed)
// =====================================================================
template <int BM, int BN, typename OutT>
__global__ __launch_bounds__(256) void gemm_mfma(
    const unsigned short* __restrict__ A, const unsigned short* __restrict__ B,
    const float* __restrict__ bias, OutT* __restrict__ C,
    int M, int N, int K) {
  constexpr int TM = BM / 32, TN = BN / 32;
  __shared__ __align__(16) unsigned short As[2][BM * 32];
  __shared__ __align__(16) unsigned short Bs[2][BN * 32];
  const int tid = threadIdx.x;
  const int wave = tid >> 6, lane = tid & 63;
  const int quad = lane >> 4, l16 = lane & 15;
  const int wm = (wave >> 1) * (BM / 2), wn = (wave & 1) * (BN / 2);
  const int m0 = blockIdx.x * BM, n0 = blockIdx.y * BN;
  const int sw = (l16 >> 1) & 3;

  f32x4 acc[TM][TN];
  #pragma unroll
  for (int i = 0; i < TM; i++)
    #pragma unroll
    for (int j = 0; j < TN; j++) acc[i][j] = {0.f, 0.f, 0.f, 0.f};

  auto stage = [&](int k0, int bb) {
    #pragma unroll
    for (int it = 0; it < BM / 64; it++) {
      int flat = it * 256 + tid;
      int row = flat >> 2;
      int cg = (flat & 3) ^ ((row >> 1) & 3);
      g2lds16(A + (size_t)(m0 + row) * K + k0 + cg * 8, &As[bb][flat * 8]);
    }
    #pragma unroll
    for (int it = 0; it < BN / 64; it++) {
      int flat = it * 256 + tid;
      int row = flat >> 2;
      int cg = (flat & 3) ^ ((row >> 1) & 3);
      g2lds16(B + (size_t)(n0 + row) * K + k0 + cg * 8, &Bs[bb][flat * 8]);
    }
  };

  stage(0, 0);
  __syncthreads();
  for (int k0 = 0; k0 < K; k0 += 32) {
    const int bb = (k0 >> 5) & 1;
    if (k0 + 32 < K) stage(k0 + 32, bb ^ 1);
    bf16x8 af[TM], bf[TN];
    #pragma unroll
    for (int i = 0; i < TM; i++)
      af[i] = *(const bf16x8*)&As[bb][(wm + i * 16 + l16) * 32 + (quad ^ sw) * 8];
    #pragma unroll
    for (int j = 0; j < TN; j++)
      bf[j] = *(const bf16x8*)&Bs[bb][(wn + j * 16 + l16) * 32 + (quad ^ sw) * 8];
    #pragma unroll
    for (int i = 0; i < TM; i++)
      #pragma unroll
      for (int j = 0; j < TN; j++)
        acc[i][j] = __builtin_amdgcn_mfma_f32_16x16x32_bf16(af[i], bf[j], acc[i][j], 0, 0, 0);
    __syncthreads();  // gates buffer reuse + drains this iter's prefetch
  }

  #pragma unroll
  for (int i = 0; i < TM; i++) {
    #pragma unroll
    for (int r = 0; r < 4; r++) {
      int m = m0 + wm + i * 16 + quad * 4 + r;
      #pragma unroll
      for (int j = 0; j < TN; j++) {
        int n = n0 + wn + j * 16 + l16;
        storev(&C[(size_t)m * N + n], acc[i][j][r] + bias[n]);
      }
    }
  }
}

// =====================================================================
// One-shot V transpose: raw-view V -> Vt[bh][d][s] bf16.
// =====================================================================
__global__ __launch_bounds__(256) void transpose_v(
    const unsigned short* __restrict__ proj, unsigned short* __restrict__ vt) {
  __shared__ unsigned short T[64][66];
  const int tid = threadIdx.x;
  const int s0 = blockIdx.x * 64, d0 = blockIdx.y * 64, bh = blockIdx.z;
  const int b = bh >> 3, h = bh & 7;
  #pragma unroll
  for (int it = 0; it < 2; it++) {
    int c = it * 256 + tid;
    int sr = c >> 3, k8 = (c & 7) * 8;
    int s = s0 + sr;
    const unsigned short* src = proj + (size_t)(b * SQL + h * 128 + (s >> 3)) * NKV
                                + 2 * 2048 + (s & 7) * 256 + d0 + k8;
    *(ulonglong2*)&T[sr][k8] = *(const ulonglong2*)src;
  }
  __syncthreads();
  #pragma unroll
  for (int it = 0; it < 2; it++) {
    int c = it * 256 + tid;
    int dr = c >> 3, s8 = (c & 7) * 8;
    unsigned short tmp[8];
    #pragma unroll
    for (int j = 0; j < 8; j++) tmp[j] = T[s8 + j][dr];
    unsigned short* dst = vt + ((size_t)bh * EDIM + d0 + dr) * SQL + s0 + s8;
    *(ulonglong2*)dst = *(ulonglong2*)tmp;
  }
}

// =====================================================================
// bf16 MFMA flash attention, round 6 (resubmit — round 2 bench was an
// infra failure, no data): occupancy 2x via 8-wave blocks.
// Round-1 lesson: wave-independence between staging barriers is sacred
// (mid-iter barrier lockstep regressed 47->57us). So: duplicated-QK
// split — wave (qs,dh): QK^T for rows qs*16..+15 over ALL 32 k-cols
// (duplicated across the dh pair; buys independence), softmax + P
// roundtrip in private Ps slice (same-wave lgkm only), PV over d-half
// dh*128..+127 (o[8] = -32 VGPR). 1 barrier/iter, kt=32 dbuf staging,
// grid/balance unchanged. 2 blocks/CU x 8 waves = 16 waves/CU = 4/SIMD
// (vs 2/SIMD before). qs<=1 waves skip the fully-masked last tile.
// LDS: Ks0|Vt0|Ks1|Vt1 (16KB each) + Ps 8x[16][40] 10KB = 75.8KB.
// =====================================================================
__global__ __launch_bounds__(512, 4) void attn_mfma(
    const unsigned short* __restrict__ proj,
    const unsigned short* __restrict__ vt,
    unsigned short* __restrict__ oflat) {
  // shorts: Ks0 @0 (8192) | Vt0 @8192 | Ks1 @16384 | Vt1 @24576 | Ps @32768 (5120)
  __shared__ __align__(16) unsigned short lds[37888];
  unsigned short* Ps = lds + 32768;  // 8 slices x [16][40]

  const int tid = threadIdx.x;          // 0..511
  const int wave = tid >> 6, lane = tid & 63;
  const int quad = lane >> 4, l16 = lane & 15;
  const int qs = wave >> 1;             // q-row subtile: rows qs*16..+15
  const int dh = wave & 1;              // PV d-half: cols dh*128..+127
  // balanced decode: slot s -> (bh = s&31, j = s>>5); round 0 heavy, 1 light
  const int slot = blockIdx.x & 255, round = blockIdx.x >> 8;
  const int bh = slot & 31;
  const int jj = slot >> 5;
  const int qt = round ? jj : 15 - jj;
  const int b = bh >> 3, h = bh & 7;
  const int q0 = qt * 64;

  // ---- stage Q (64 x 256) through buf0 region (16K shorts), swizzled ----
  #pragma unroll
  for (int it = 0; it < 4; it++) {
    int c = it * 512 + tid;
    int r = c >> 5, ch = (c & 31) ^ (r & 7);
    int s = q0 + r;
    g2lds16(proj + (size_t)(b * SQL + h * 128 + (s >> 3)) * NKV + (s & 7) * 256 + ch * 8,
            lds + c * 8);
  }
  __syncthreads();
  bf16x8 aq[8];
  const int qrow = qs * 16 + l16;
  #pragma unroll
  for (int kk = 0; kk < 8; kk++)
    aq[kk] = *(const bf16x8*)&lds[qrow * 256 + ((kk * 4 + quad) ^ (qrow & 7)) * 8];
  __syncthreads();  // all waves done reading Q before buf0 overwrite

  f32x4 o[8];
  #pragma unroll
  for (int t = 0; t < 8; t++) o[t] = {0.f, 0.f, 0.f, 0.f};
  float l_r[4] = {0.f, 0.f, 0.f, 0.f};

  auto stage = [&](int kt, int bb) {
    unsigned short* KsB = lds + bb * 16384;
    unsigned short* VtB = KsB + 8192;
    #pragma unroll
    for (int it = 0; it < 2; it++) {   // K tile 32 x 256
      int c = it * 512 + tid;
      int r = c >> 5, ch = (c & 31) ^ (r & 7);
      int s = kt * 32 + r;
      g2lds16(proj + (size_t)(b * SQL + h * 128 + (s >> 3)) * NKV + 2048 + (s & 7) * 256 + ch * 8,
              KsB + c * 8);
    }
    #pragma unroll
    for (int it = 0; it < 2; it++) {   // Vt tile 256 x 32
      int c = it * 512 + tid;
      int d = c >> 2, ch = (c & 3) ^ (d & 3);
      g2lds16(vt + ((size_t)bh * EDIM + d) * SQL + kt * 32 + ch * 8, VtB + c * 8);
    }
  };

  const int nkt = 2 * qt + 2;
  stage(0, 0);
  __syncthreads();  // drain kt=0 (exposed once)

  for (int kt = 0; kt < nkt; kt++) {
    const int bb = kt & 1;
    if (kt + 1 < nkt) stage(kt + 1, bb ^ 1);  // prefetch into other buffer
    const unsigned short* KsB = lds + bb * 16384;
    const unsigned short* VtB = KsB + 8192;
    // qs<=1 waves are fully masked on the last (diagonal) tile
    const bool live = (kt * 32 <= q0 + qs * 16 + 15);

    if (live) {
      // ---- S = Q K^T (two 16-col tiles), full 32 k-cols per wave ----
      f32x4 s0 = {0.f, 0.f, 0.f, 0.f}, s1 = {0.f, 0.f, 0.f, 0.f};
      #pragma unroll
      for (int kk = 0; kk < 8; kk++) {
        int ch = (kk * 4 + quad) ^ (l16 & 7);
        bf16x8 b0 = *(const bf16x8*)&KsB[l16 * 256 + ch * 8];
        bf16x8 b1 = *(const bf16x8*)&KsB[(16 + l16) * 256 + ch * 8];
        s0 = __builtin_amdgcn_mfma_f32_16x16x32_bf16(aq[kk], b0, s0, 0, 0, 0);
        s1 = __builtin_amdgcn_mfma_f32_16x16x32_bf16(aq[kk], b1, s1, 0, 0, 0);
      }

      // ---- shift-free softmax: p = exp2(s/16*log2e), lane-local l ----
      const int kg0 = kt * 32 + l16, kg1 = kg0 + 16;
      unsigned short* PsW = Ps + wave * 640;  // private [16][40] slice
      #pragma unroll
      for (int r = 0; r < 4; r++) {
        int qg = q0 + qs * 16 + quad * 4 + r;
        float p0 = (kg0 <= qg) ? exp2f(s0[r] * 0.09016844f) : 0.f;
        float p1 = (kg1 <= qg) ? exp2f(s1[r] * 0.09016844f) : 0.f;
        l_r[r] += p0 + p1;
        PsW[(quad * 4 + r) * 40 + l16]      = f2bf(p0);
        PsW[(quad * 4 + r) * 40 + 16 + l16] = f2bf(p1);
      }

      // ---- PV over d-half: P C->A layout via same-wave LDS round-trip ----
      bf16x8 ap = *(const bf16x8*)&PsW[l16 * 40 + quad * 8];
      #pragma unroll
      for (int tl = 0; tl < 8; tl++) {
        const int vrow = dh * 128 + tl * 16 + l16;
        bf16x8 bv = *(const bf16x8*)&VtB[vrow * 32 + (quad ^ (l16 & 3)) * 8];
        o[tl] = __builtin_amdgcn_mfma_f32_16x16x32_bf16(ap, bv, o[tl], 0, 0, 0);
      }
    }
    __syncthreads();  // buffer reuse gate + drains this iter's prefetch
  }

  // ---- epilogue: reduce l across the 16-lane group, O /= l, scatter ----
  #pragma unroll
  for (int r = 0; r < 4; r++) {
    float l = l_r[r];
    #pragma unroll
    for (int off = 1; off < 16; off <<= 1) l += __shfl_xor(l, off);
    float inv = 1.0f / l;
    int s = q0 + qs * 16 + quad * 4 + r;
    unsigned short* dst = oflat + (size_t)(b * SQL + h * 128 + (s >> 3)) * 2048
                          + (s & 7) * 256 + dh * 128;
    #pragma unroll
    for (int tl = 0; tl < 8; tl++)
      dst[tl * 16 + l16] = f2bf(o[tl][r] * inv);
  }
}

extern "C" void kernel_launch(void* const* d_in, const int* in_sizes, int n_in,
                              void* d_out, int out_size, void* d_ws, size_t ws_size,
                              hipStream_t stream) {
  const float* x      = (const float*)d_in[0];
  const float* w_attn = (const float*)d_in[1];
  const float* b_attn = (const float*)d_in[2];
  const float* w_out  = (const float*)d_in[3];
  const float* b_out  = (const float*)d_in[4];
  float* out = (float*)d_out;

  char* p = (char*)d_ws;
  unsigned short* proj = (unsigned short*)p;  p += (size_t)MROWS * NKV * 2;
  unsigned short* obf  = (unsigned short*)p;  p += (size_t)MROWS * 2048 * 2;
  unsigned short* vtb  = (unsigned short*)p;  p += (size_t)32 * EDIM * SQL * 2;
  unsigned short* xb   = (unsigned short*)p;  p += (size_t)MROWS * EDIM * 2;
  unsigned short* wb   = (unsigned short*)p;  p += (size_t)NKV * EDIM * 2;
  unsigned short* wob  = (unsigned short*)p;

  const int n0 = MROWS * EDIM / 8;        // 131072 -> 512 blocks
  const int n1 = NKV * EDIM / 8;          // 196608 -> 768 blocks
  const int n2 = EDIM * 2048 / 8;         // 65536  -> 256 blocks
  cast3_bf16<<<(n0 + n1 + n2) / 256, 256, 0, stream>>>(x, xb, n0, w_attn, wb, n1,
                                                       w_out, wob, n2);

  gemm_mfma<128, 128, unsigned short><<<dim3(MROWS / 128, NKV / 128), 256, 0, stream>>>(
      xb, wb, b_attn, proj, MROWS, NKV, EDIM);
  transpose_v<<<dim3(SQL / 64, EDIM / 64, 32), 256, 0, stream>>>(proj, vtb);
  attn_mfma<<<512, 512, 0, stream>>>(proj, vtb, obf);
  gemm_mfma<64, 64, float><<<dim3(MROWS / 64, EDIM / 64), 256, 0, stream>>>(
      obf, wob, b_out, out, MROWS, EDIM, NHD * EDIM);
}